// Round 3
// baseline (3471.775 us; speedup 1.0000x reference)
//
#include <hip/hip_runtime.h>
#include <hip/hip_bf16.h>

#define D_MODEL 2048
#define N_HEAD 32
#define N_KV_HEAD 8
#define N_REP 4
#define D_K 64
#define S_LEN 1024
#define B_SZ 2
#define M_ROWS (B_SZ * S_LEN)      // 2048
#define KV_DIM (N_KV_HEAD * D_K)   // 512

// C[M,N] = A[M,K] @ W[K,N] + bias[N]; all fp32.
// BM=BN=64, BK=16, 256 threads, 4x4 micro-tile per thread.
__global__ void gemm_bias_kernel(const float* __restrict__ A,
                                 const float* __restrict__ W,
                                 const float* __restrict__ bias,
                                 float* __restrict__ C, int M, int N, int K) {
    const int BM = 64, BN = 64, BK = 16;
    __shared__ float As[BK][BM + 1];
    __shared__ float Ws[BK][BN + 1];
    const int bm = blockIdx.y * BM;
    const int bn = blockIdx.x * BN;
    const int tid = threadIdx.x;            // 0..255
    const int tn = tid & 15;
    const int tm = tid >> 4;
    float acc[4][4] = {};
    for (int k0 = 0; k0 < K; k0 += BK) {
        {   // A tile: 64 rows x 16 k
            int r = tid >> 2;
            int c4 = (tid & 3) * 4;
            const float* ap = A + (size_t)(bm + r) * K + k0 + c4;
#pragma unroll
            for (int i = 0; i < 4; i++) As[c4 + i][r] = ap[i];
        }
        {   // W tile: 16 k x 64 cols
            int r = tid >> 4;
            int c4 = (tid & 15) * 4;
            const float* wp = W + (size_t)(k0 + r) * N + bn + c4;
#pragma unroll
            for (int i = 0; i < 4; i++) Ws[r][c4 + i] = wp[i];
        }
        __syncthreads();
#pragma unroll
        for (int kk = 0; kk < BK; kk++) {
            float a[4], w[4];
#pragma unroll
            for (int i = 0; i < 4; i++) a[i] = As[kk][tm * 4 + i];
#pragma unroll
            for (int j = 0; j < 4; j++) w[j] = Ws[kk][tn * 4 + j];
#pragma unroll
            for (int i = 0; i < 4; i++)
#pragma unroll
                for (int j = 0; j < 4; j++) acc[i][j] += a[i] * w[j];
        }
        __syncthreads();
    }
#pragma unroll
    for (int i = 0; i < 4; i++) {
        int row = bm + tm * 4 + i;
#pragma unroll
        for (int j = 0; j < 4; j++) {
            int col = bn + tn * 4 + j;
            C[(size_t)row * N + col] = acc[i][j] + bias[col];
        }
    }
}

// In-place RoPE on t: [M_ROWS, n_heads*D_K] fp32.
__global__ void rope_kernel(float* __restrict__ t, int n_heads) {
    const int half = D_K / 2;  // 32
    int idx = blockIdx.x * blockDim.x + threadIdx.x;
    int total = M_ROWS * n_heads * half;
    if (idx >= total) return;
    int i = idx % half;
    int h = (idx / half) % n_heads;
    int r = idx / (half * n_heads);
    int s = r % S_LEN;
    float inv_freq = powf(10000.0f, -2.0f * (float)i / (float)D_K);
    float ang = (float)s * inv_freq;
    float c = cosf(ang), sn = sinf(ang);
    float* p = t + (size_t)r * (n_heads * D_K) + h * D_K + 2 * i;
    float te = p[0], to = p[1];
    p[0] = te * c - to * sn;
    p[1] = te * sn + to * c;
}

// One wave per (b,h,s) query row; lane = d. Online softmax (finite init), causal.
// o may alias q: each block reads only its own q row (before writing it).
__global__ void attn_kernel(const float* __restrict__ q, const float* __restrict__ k,
                            const float* __restrict__ v, float* __restrict__ o) {
    int s = blockIdx.x, h = blockIdx.y, b = blockIdx.z;
    int d = threadIdx.x;  // 0..63
    int kvh = h >> 2;     // N_REP = 4
    float qd = q[((size_t)(b * S_LEN + s)) * D_MODEL + h * D_K + d] * 0.125f;  // 1/sqrt(64)
    const float* kbase = k + (size_t)b * S_LEN * KV_DIM + kvh * D_K + d;
    const float* vbase = v + (size_t)b * S_LEN * KV_DIM + kvh * D_K + d;
    float m = -1e30f, l = 0.f, acc = 0.f;
    for (int j = 0; j <= s; j++) {
        float prod = qd * kbase[(size_t)j * KV_DIM];
#pragma unroll
        for (int off = 32; off > 0; off >>= 1) prod += __shfl_xor(prod, off, 64);
        float score = prod;
        float mnew = fmaxf(m, score);
        float corr = __expf(m - mnew);   // m finite; exp(very negative) -> 0
        float p = __expf(score - mnew);
        l = l * corr + p;
        acc = acc * corr + p * vbase[(size_t)j * KV_DIM];
        m = mnew;
    }
    o[((size_t)(b * S_LEN + s)) * D_MODEL + h * D_K + d] = acc / l;
}

extern "C" void kernel_launch(void* const* d_in, const int* in_sizes, int n_in,
                              void* d_out, int out_size, void* d_ws, size_t ws_size,
                              hipStream_t stream) {
    const float* x  = (const float*)d_in[0];
    const float* Wq = (const float*)d_in[1];
    const float* bq = (const float*)d_in[2];
    const float* Wk = (const float*)d_in[3];
    const float* bk = (const float*)d_in[4];
    const float* Wv = (const float*)d_in[5];
    const float* bv = (const float*)d_in[6];
    const float* Wo = (const float*)d_in[7];
    const float* bo = (const float*)d_in[8];
    float* out = (float*)d_out;

    // workspace (fp32): q 4M elems (16MB), k 1M (4MB), v 1M (4MB); attn out aliases q
    float* qws = (float*)d_ws;
    float* kws = qws + (size_t)M_ROWS * D_MODEL;
    float* vws = kws + (size_t)M_ROWS * KV_DIM;
    float* aws = qws;  // alias: attn writes its own q row only after reading it

    dim3 blk(256);
    gemm_bias_kernel<<<dim3(D_MODEL / 64, M_ROWS / 64), blk, 0, stream>>>(x, Wq, bq, qws, M_ROWS, D_MODEL, D_MODEL);
    gemm_bias_kernel<<<dim3(KV_DIM / 64, M_ROWS / 64), blk, 0, stream>>>(x, Wk, bk, kws, M_ROWS, KV_DIM, D_MODEL);
    gemm_bias_kernel<<<dim3(KV_DIM / 64, M_ROWS / 64), blk, 0, stream>>>(x, Wv, bv, vws, M_ROWS, KV_DIM, D_MODEL);
    rope_kernel<<<(M_ROWS * N_HEAD * (D_K / 2) + 255) / 256, blk, 0, stream>>>(qws, N_HEAD);
    rope_kernel<<<(M_ROWS * N_KV_HEAD * (D_K / 2) + 255) / 256, blk, 0, stream>>>(kws, N_KV_HEAD);
    attn_kernel<<<dim3(S_LEN, N_HEAD, B_SZ), dim3(64), 0, stream>>>(qws, kws, vws, aws);
    gemm_bias_kernel<<<dim3(D_MODEL / 64, M_ROWS / 64), blk, 0, stream>>>(aws, Wo, bo, out, M_ROWS, D_MODEL, D_MODEL);
}

// Round 4
// 1835.716 us; speedup vs baseline: 1.8912x; 1.8912x over previous
//
#include <hip/hip_runtime.h>
#include <hip/hip_bf16.h>

#define D_MODEL 2048
#define N_HEAD 32
#define N_KV_HEAD 8
#define N_REP 4
#define D_K 64
#define S_LEN 1024
#define B_SZ 2
#define M_ROWS (B_SZ * S_LEN)      // 2048
#define KV_DIM (N_KV_HEAD * D_K)   // 512

// C[M,N] = A[M,K] @ W[K,N] + bias[N]; all fp32.
// BM=BN=64, BK=16, 256 threads, 4x4 micro-tile per thread.
__global__ void gemm_bias_kernel(const float* __restrict__ A,
                                 const float* __restrict__ W,
                                 const float* __restrict__ bias,
                                 float* __restrict__ C, int M, int N, int K) {
    const int BM = 64, BN = 64, BK = 16;
    __shared__ float As[BK][BM + 1];
    __shared__ float Ws[BK][BN + 1];
    const int bm = blockIdx.y * BM;
    const int bn = blockIdx.x * BN;
    const int tid = threadIdx.x;            // 0..255
    const int tn = tid & 15;
    const int tm = tid >> 4;
    float acc[4][4] = {};
    for (int k0 = 0; k0 < K; k0 += BK) {
        {   // A tile: 64 rows x 16 k
            int r = tid >> 2;
            int c4 = (tid & 3) * 4;
            const float* ap = A + (size_t)(bm + r) * K + k0 + c4;
#pragma unroll
            for (int i = 0; i < 4; i++) As[c4 + i][r] = ap[i];
        }
        {   // W tile: 16 k x 64 cols
            int r = tid >> 4;
            int c4 = (tid & 15) * 4;
            const float* wp = W + (size_t)(k0 + r) * N + bn + c4;
#pragma unroll
            for (int i = 0; i < 4; i++) Ws[r][c4 + i] = wp[i];
        }
        __syncthreads();
#pragma unroll
        for (int kk = 0; kk < BK; kk++) {
            float a[4], w[4];
#pragma unroll
            for (int i = 0; i < 4; i++) a[i] = As[kk][tm * 4 + i];
#pragma unroll
            for (int j = 0; j < 4; j++) w[j] = Ws[kk][tn * 4 + j];
#pragma unroll
            for (int i = 0; i < 4; i++)
#pragma unroll
                for (int j = 0; j < 4; j++) acc[i][j] += a[i] * w[j];
        }
        __syncthreads();
    }
#pragma unroll
    for (int i = 0; i < 4; i++) {
        int row = bm + tm * 4 + i;
#pragma unroll
        for (int j = 0; j < 4; j++) {
            int col = bn + tn * 4 + j;
            C[(size_t)row * N + col] = acc[i][j] + bias[col];
        }
    }
}

// In-place RoPE on t: [M_ROWS, n_heads*D_K] fp32.
__global__ void rope_kernel(float* __restrict__ t, int n_heads) {
    const int half = D_K / 2;  // 32
    int idx = blockIdx.x * blockDim.x + threadIdx.x;
    int total = M_ROWS * n_heads * half;
    if (idx >= total) return;
    int i = idx % half;
    int h = (idx / half) % n_heads;
    int r = idx / (half * n_heads);
    int s = r % S_LEN;
    float inv_freq = powf(10000.0f, -2.0f * (float)i / (float)D_K);
    float ang = (float)s * inv_freq;
    float c = cosf(ang), sn = sinf(ang);
    float* p = t + (size_t)r * (n_heads * D_K) + h * D_K + 2 * i;
    float te = p[0], to = p[1];
    p[0] = te * c - to * sn;
    p[1] = te * sn + to * c;
}

// Flash-style causal attention: block = 128 threads = 128 consecutive query rows
// of one (b,h). K/V tiles (64 keys x 64 dims) staged in LDS; each thread keeps
// q[64] and acc[64] in registers; LDS reads are wave-uniform (broadcast).
// o may alias q: each block writes only the q rows it read.
#define ROWS_PB 128
#define TKEYS 64
__global__ __launch_bounds__(ROWS_PB) void attn_flash_kernel(
        const float* __restrict__ q, const float* __restrict__ k,
        const float* __restrict__ v, float* __restrict__ o) {
    __shared__ float Ks[TKEYS * D_K];   // 16 KB
    __shared__ float Vs[TKEYS * D_K];   // 16 KB
    const int tid = threadIdx.x;        // 0..127
    const int q0 = blockIdx.x * ROWS_PB;
    const int h = blockIdx.y, b = blockIdx.z;
    const int kvh = h >> 2;             // N_REP = 4
    const int s = q0 + tid;             // this thread's query row

    const float* qrow = q + ((size_t)(b * S_LEN + s)) * D_MODEL + h * D_K;
    float4 qf[16];
#pragma unroll
    for (int i = 0; i < 16; i++) {
        float4 t = ((const float4*)qrow)[i];
        t.x *= 0.125f; t.y *= 0.125f; t.z *= 0.125f; t.w *= 0.125f;  // 1/sqrt(64)
        qf[i] = t;
    }
    float4 accf[16];
#pragma unroll
    for (int i = 0; i < 16; i++) accf[i] = make_float4(0.f, 0.f, 0.f, 0.f);
    float m = -1e30f, l = 0.f;

    const float* kb = k + (size_t)b * S_LEN * KV_DIM + kvh * D_K;
    const float* vb = v + (size_t)b * S_LEN * KV_DIM + kvh * D_K;

    for (int j0 = 0; j0 < q0 + ROWS_PB; j0 += TKEYS) {
        __syncthreads();
        // stage 64 keys x 64 dims of K and V: 4096 floats = 1024 float4 each;
        // 128 threads -> 8 float4 per thread; consecutive tid -> contiguous global.
#pragma unroll
        for (int it = 0; it < 8; it++) {
            int f = it * 128 + tid;          // float4 index
            int row = f >> 4, c4 = f & 15;   // 16 float4 per key row
            ((float4*)Ks)[f] = ((const float4*)(kb + (size_t)(j0 + row) * KV_DIM))[c4];
            ((float4*)Vs)[f] = ((const float4*)(vb + (size_t)(j0 + row) * KV_DIM))[c4];
        }
        __syncthreads();

        const bool tile_masked = (j0 + TKEYS - 1 > s);
        for (int jj = 0; jj < TKEYS; jj++) {
            float dot = 0.f;
#pragma unroll
            for (int i = 0; i < 16; i++) {
                float4 kv = ((const float4*)Ks)[jj * 16 + i];
                dot += qf[i].x * kv.x + qf[i].y * kv.y + qf[i].z * kv.z + qf[i].w * kv.w;
            }
            if (tile_masked && (j0 + jj > s)) dot = -1e30f;
            if (dot > m) {                   // rare after warm-up (flash-2 rescale)
                float corr = __expf(m - dot);
                l *= corr;
#pragma unroll
                for (int i = 0; i < 16; i++) {
                    accf[i].x *= corr; accf[i].y *= corr;
                    accf[i].z *= corr; accf[i].w *= corr;
                }
                m = dot;
            }
            float p = __expf(dot - m);       // masked: exp(-huge) = 0
            l += p;
#pragma unroll
            for (int i = 0; i < 16; i++) {
                float4 vv = ((const float4*)Vs)[jj * 16 + i];
                accf[i].x += p * vv.x; accf[i].y += p * vv.y;
                accf[i].z += p * vv.z; accf[i].w += p * vv.w;
            }
        }
    }
    float inv_l = 1.f / l;
    float* orow = o + ((size_t)(b * S_LEN + s)) * D_MODEL + h * D_K;
#pragma unroll
    for (int i = 0; i < 16; i++) {
        float4 t = accf[i];
        t.x *= inv_l; t.y *= inv_l; t.z *= inv_l; t.w *= inv_l;
        ((float4*)orow)[i] = t;
    }
}

extern "C" void kernel_launch(void* const* d_in, const int* in_sizes, int n_in,
                              void* d_out, int out_size, void* d_ws, size_t ws_size,
                              hipStream_t stream) {
    const float* x  = (const float*)d_in[0];
    const float* Wq = (const float*)d_in[1];
    const float* bq = (const float*)d_in[2];
    const float* Wk = (const float*)d_in[3];
    const float* bk = (const float*)d_in[4];
    const float* Wv = (const float*)d_in[5];
    const float* bv = (const float*)d_in[6];
    const float* Wo = (const float*)d_in[7];
    const float* bo = (const float*)d_in[8];
    float* out = (float*)d_out;

    // workspace (fp32): q 4M elems (16MB), k 1M (4MB), v 1M (4MB); attn out aliases q
    float* qws = (float*)d_ws;
    float* kws = qws + (size_t)M_ROWS * D_MODEL;
    float* vws = kws + (size_t)M_ROWS * KV_DIM;
    float* aws = qws;  // alias: each attn block writes only the q rows it read

    dim3 blk(256);
    gemm_bias_kernel<<<dim3(D_MODEL / 64, M_ROWS / 64), blk, 0, stream>>>(x, Wq, bq, qws, M_ROWS, D_MODEL, D_MODEL);
    gemm_bias_kernel<<<dim3(KV_DIM / 64, M_ROWS / 64), blk, 0, stream>>>(x, Wk, bk, kws, M_ROWS, KV_DIM, D_MODEL);
    gemm_bias_kernel<<<dim3(KV_DIM / 64, M_ROWS / 64), blk, 0, stream>>>(x, Wv, bv, vws, M_ROWS, KV_DIM, D_MODEL);
    rope_kernel<<<(M_ROWS * N_HEAD * (D_K / 2) + 255) / 256, blk, 0, stream>>>(qws, N_HEAD);
    rope_kernel<<<(M_ROWS * N_KV_HEAD * (D_K / 2) + 255) / 256, blk, 0, stream>>>(kws, N_KV_HEAD);
    attn_flash_kernel<<<dim3(S_LEN / ROWS_PB, N_HEAD, B_SZ), dim3(ROWS_PB), 0, stream>>>(qws, kws, vws, aws);
    gemm_bias_kernel<<<dim3(D_MODEL / 64, M_ROWS / 64), blk, 0, stream>>>(aws, Wo, bo, out, M_ROWS, D_MODEL, D_MODEL);
}

// Round 5
// 1057.468 us; speedup vs baseline: 3.2831x; 1.7360x over previous
//
#include <hip/hip_runtime.h>
#include <hip/hip_bf16.h>

#define D_MODEL 2048
#define N_HEAD 32
#define N_KV_HEAD 8
#define N_REP 4
#define D_K 64
#define S_LEN 1024
#define B_SZ 2
#define M_ROWS (B_SZ * S_LEN)      // 2048
#define KV_DIM (N_KV_HEAD * D_K)   // 512

typedef __attribute__((ext_vector_type(8))) short short8;   // 8 bf16 (4 VGPRs)
typedef __attribute__((ext_vector_type(4))) float f32x4;

__device__ inline unsigned short f2bf(float f) {  // RNE fp32 -> bf16 bits
    union { float f; unsigned int u; } x{f};
    unsigned int r = x.u + 0x7fffu + ((x.u >> 16) & 1u);
    return (unsigned short)(r >> 16);
}

// ---------------- transpose + cast: W[K,N] fp32 -> Wt[N,K] bf16 ----------------
__global__ void transpose_cast_kernel(const float* __restrict__ W,
                                      unsigned short* __restrict__ Wt,
                                      int K, int N) {
    __shared__ float tile[32][33];
    int n0 = blockIdx.x * 32, k0 = blockIdx.y * 32;
    int tx = threadIdx.x, ty = threadIdx.y;   // 32 x 8
#pragma unroll
    for (int r = 0; r < 4; r++)
        tile[ty * 4 + r][tx] = W[(size_t)(k0 + ty * 4 + r) * N + n0 + tx];
    __syncthreads();
#pragma unroll
    for (int r = 0; r < 4; r++)
        Wt[(size_t)(n0 + ty * 4 + r) * K + k0 + tx] = f2bf(tile[tx][ty * 4 + r]);
}

// ---------------- bf16 MFMA GEMM: C[M,N] = A[M,K] * Wt[N,K]^T + bias ----------
// A fp32 (cast to bf16 while staging), Wt bf16 (pre-transposed), C fp32.
// BM=BN=64, BK=64, 256 threads = 4 waves; wave computes 32x32 (2x2 16x16 frags).
#define GSTRIDE 72   // LDS row stride in bf16 elems (64 + 8 pad); 144 B, 16B-aligned
__global__ __launch_bounds__(256) void gemm_mfma_kernel(
        const float* __restrict__ A, const unsigned short* __restrict__ Wt,
        const float* __restrict__ bias, float* __restrict__ C,
        int M, int N, int K) {
    __shared__ unsigned short As[64 * GSTRIDE];
    __shared__ unsigned short Bs[64 * GSTRIDE];
    const int tid = threadIdx.x;
    const int lane = tid & 63;
    const int w = tid >> 6;            // wave 0..3
    const int wm = w >> 1, wn = w & 1; // wave quadrant (32x32)
    const int bm = blockIdx.y * 64, bn = blockIdx.x * 64;

    f32x4 acc[2][2];
#pragma unroll
    for (int i = 0; i < 2; i++)
#pragma unroll
        for (int j = 0; j < 2; j++) acc[i][j] = (f32x4){0.f, 0.f, 0.f, 0.f};

    const int qd = lane >> 4;          // quad 0..3
    const int lr = lane & 15;

    for (int k0 = 0; k0 < K; k0 += 64) {
        __syncthreads();
        // stage A: 64 rows x 64 k, fp32 -> bf16. 512 chunks of 8 elems.
#pragma unroll
        for (int it = 0; it < 2; it++) {
            int c = it * 256 + tid;
            int row = c >> 3, k8 = (c & 7) * 8;
            const float4* src = (const float4*)(A + (size_t)(bm + row) * K + k0 + k8);
            float4 a0 = src[0], a1 = src[1];
            unsigned short* dst = &As[row * GSTRIDE + k8];
            dst[0] = f2bf(a0.x); dst[1] = f2bf(a0.y); dst[2] = f2bf(a0.z); dst[3] = f2bf(a0.w);
            dst[4] = f2bf(a1.x); dst[5] = f2bf(a1.y); dst[6] = f2bf(a1.z); dst[7] = f2bf(a1.w);
        }
        // stage B: 64 rows (n) x 64 k, bf16 copy (uint4 = 8 elems).
#pragma unroll
        for (int it = 0; it < 2; it++) {
            int c = it * 256 + tid;
            int row = c >> 3, k8 = (c & 7) * 8;
            *(uint4*)&Bs[row * GSTRIDE + k8] =
                *(const uint4*)(Wt + (size_t)(bn + row) * K + k0 + k8);
        }
        __syncthreads();
#pragma unroll
        for (int ks = 0; ks < 2; ks++) {
            short8 af[2], bf[2];
#pragma unroll
            for (int i = 0; i < 2; i++)
                af[i] = *(const short8*)&As[(wm * 32 + i * 16 + lr) * GSTRIDE + ks * 32 + qd * 8];
#pragma unroll
            for (int j = 0; j < 2; j++)
                bf[j] = *(const short8*)&Bs[(wn * 32 + j * 16 + lr) * GSTRIDE + ks * 32 + qd * 8];
#pragma unroll
            for (int i = 0; i < 2; i++)
#pragma unroll
                for (int j = 0; j < 2; j++)
                    acc[i][j] = __builtin_amdgcn_mfma_f32_16x16x32_bf16(af[i], bf[j], acc[i][j], 0, 0, 0);
        }
    }
    // epilogue: C/D layout col = lane&15, row = (lane>>4)*4 + reg
#pragma unroll
    for (int i = 0; i < 2; i++) {
#pragma unroll
        for (int j = 0; j < 2; j++) {
            int row0 = bm + wm * 32 + i * 16 + qd * 4;
            int col = bn + wn * 32 + j * 16 + lr;
            float bj = bias[col];
#pragma unroll
            for (int r = 0; r < 4; r++)
                C[(size_t)(row0 + r) * N + col] = acc[i][j][r] + bj;
        }
    }
}

// ---------------- RoPE (in-place, fp32) ----------------
__global__ void rope_kernel(float* __restrict__ t, int n_heads) {
    const int half = D_K / 2;  // 32
    int idx = blockIdx.x * blockDim.x + threadIdx.x;
    int total = M_ROWS * n_heads * half;
    if (idx >= total) return;
    int i = idx % half;
    int h = (idx / half) % n_heads;
    int r = idx / (half * n_heads);
    int s = r % S_LEN;
    float inv_freq = powf(10000.0f, -2.0f * (float)i / (float)D_K);
    float ang = (float)s * inv_freq;
    float c = cosf(ang), sn = sinf(ang);
    float* p = t + (size_t)r * (n_heads * D_K) + h * D_K + 2 * i;
    float te = p[0], to = p[1];
    p[0] = te * c - to * sn;
    p[1] = te * sn + to * c;
}

// ---------------- flash attention (unchanged from round 4) ----------------
#define ROWS_PB 128
#define TKEYS 64
__global__ __launch_bounds__(ROWS_PB) void attn_flash_kernel(
        const float* __restrict__ q, const float* __restrict__ k,
        const float* __restrict__ v, float* __restrict__ o) {
    __shared__ float Ks[TKEYS * D_K];
    __shared__ float Vs[TKEYS * D_K];
    const int tid = threadIdx.x;
    const int q0 = blockIdx.x * ROWS_PB;
    const int h = blockIdx.y, b = blockIdx.z;
    const int kvh = h >> 2;
    const int s = q0 + tid;

    const float* qrow = q + ((size_t)(b * S_LEN + s)) * D_MODEL + h * D_K;
    float4 qf[16];
#pragma unroll
    for (int i = 0; i < 16; i++) {
        float4 t = ((const float4*)qrow)[i];
        t.x *= 0.125f; t.y *= 0.125f; t.z *= 0.125f; t.w *= 0.125f;
        qf[i] = t;
    }
    float4 accf[16];
#pragma unroll
    for (int i = 0; i < 16; i++) accf[i] = make_float4(0.f, 0.f, 0.f, 0.f);
    float m = -1e30f, l = 0.f;

    const float* kb = k + (size_t)b * S_LEN * KV_DIM + kvh * D_K;
    const float* vb = v + (size_t)b * S_LEN * KV_DIM + kvh * D_K;

    for (int j0 = 0; j0 < q0 + ROWS_PB; j0 += TKEYS) {
        __syncthreads();
#pragma unroll
        for (int it = 0; it < 8; it++) {
            int f = it * 128 + tid;
            int row = f >> 4, c4 = f & 15;
            ((float4*)Ks)[f] = ((const float4*)(kb + (size_t)(j0 + row) * KV_DIM))[c4];
            ((float4*)Vs)[f] = ((const float4*)(vb + (size_t)(j0 + row) * KV_DIM))[c4];
        }
        __syncthreads();

        const bool tile_masked = (j0 + TKEYS - 1 > s);
        for (int jj = 0; jj < TKEYS; jj++) {
            float dot = 0.f;
#pragma unroll
            for (int i = 0; i < 16; i++) {
                float4 kv = ((const float4*)Ks)[jj * 16 + i];
                dot += qf[i].x * kv.x + qf[i].y * kv.y + qf[i].z * kv.z + qf[i].w * kv.w;
            }
            if (tile_masked && (j0 + jj > s)) dot = -1e30f;
            if (dot > m) {
                float corr = __expf(m - dot);
                l *= corr;
#pragma unroll
                for (int i = 0; i < 16; i++) {
                    accf[i].x *= corr; accf[i].y *= corr;
                    accf[i].z *= corr; accf[i].w *= corr;
                }
                m = dot;
            }
            float p = __expf(dot - m);
            l += p;
#pragma unroll
            for (int i = 0; i < 16; i++) {
                float4 vv = ((const float4*)Vs)[jj * 16 + i];
                accf[i].x += p * vv.x; accf[i].y += p * vv.y;
                accf[i].z += p * vv.z; accf[i].w += p * vv.w;
            }
        }
    }
    float inv_l = 1.f / l;
    float* orow = o + ((size_t)(b * S_LEN + s)) * D_MODEL + h * D_K;
#pragma unroll
    for (int i = 0; i < 16; i++) {
        float4 t = accf[i];
        t.x *= inv_l; t.y *= inv_l; t.z *= inv_l; t.w *= inv_l;
        ((float4*)orow)[i] = t;
    }
}

extern "C" void kernel_launch(void* const* d_in, const int* in_sizes, int n_in,
                              void* d_out, int out_size, void* d_ws, size_t ws_size,
                              hipStream_t stream) {
    const float* x  = (const float*)d_in[0];
    const float* Wq = (const float*)d_in[1];
    const float* bq = (const float*)d_in[2];
    const float* Wk = (const float*)d_in[3];
    const float* bk = (const float*)d_in[4];
    const float* Wv = (const float*)d_in[5];
    const float* bv = (const float*)d_in[6];
    const float* Wo = (const float*)d_in[7];
    const float* bo = (const float*)d_in[8];
    float* out = (float*)d_out;

    // ws: qws 16MB | kws 4MB | vws 4MB | Wt 8MB (reused for all 4 weights) = 32MB
    float* qws = (float*)d_ws;
    float* kws = qws + (size_t)M_ROWS * D_MODEL;
    float* vws = kws + (size_t)M_ROWS * KV_DIM;
    unsigned short* Wt = (unsigned short*)(vws + (size_t)M_ROWS * KV_DIM);
    float* aws = qws;  // attn out aliases q (each block writes only rows it read)

    dim3 tb(32, 8);
    dim3 gb(256);

    // Q proj
    transpose_cast_kernel<<<dim3(D_MODEL / 32, D_MODEL / 32), tb, 0, stream>>>(Wq, Wt, D_MODEL, D_MODEL);
    gemm_mfma_kernel<<<dim3(D_MODEL / 64, M_ROWS / 64), gb, 0, stream>>>(x, Wt, bq, qws, M_ROWS, D_MODEL, D_MODEL);
    // K proj
    transpose_cast_kernel<<<dim3(KV_DIM / 32, D_MODEL / 32), tb, 0, stream>>>(Wk, Wt, D_MODEL, KV_DIM);
    gemm_mfma_kernel<<<dim3(KV_DIM / 64, M_ROWS / 64), gb, 0, stream>>>(x, Wt, bk, kws, M_ROWS, KV_DIM, D_MODEL);
    // V proj
    transpose_cast_kernel<<<dim3(KV_DIM / 32, D_MODEL / 32), tb, 0, stream>>>(Wv, Wt, D_MODEL, KV_DIM);
    gemm_mfma_kernel<<<dim3(KV_DIM / 64, M_ROWS / 64), gb, 0, stream>>>(x, Wt, bv, vws, M_ROWS, KV_DIM, D_MODEL);
    // RoPE
    rope_kernel<<<(M_ROWS * N_HEAD * (D_K / 2) + 255) / 256, gb, 0, stream>>>(qws, N_HEAD);
    rope_kernel<<<(M_ROWS * N_KV_HEAD * (D_K / 2) + 255) / 256, gb, 0, stream>>>(kws, N_KV_HEAD);
    // attention
    attn_flash_kernel<<<dim3(S_LEN / ROWS_PB, N_HEAD, B_SZ), dim3(ROWS_PB), 0, stream>>>(qws, kws, vws, aws);
    // O proj
    transpose_cast_kernel<<<dim3(D_MODEL / 32, D_MODEL / 32), tb, 0, stream>>>(Wo, Wt, D_MODEL, D_MODEL);
    gemm_mfma_kernel<<<dim3(D_MODEL / 64, M_ROWS / 64), gb, 0, stream>>>(aws, Wt, bo, out, M_ROWS, D_MODEL, D_MODEL);
}

// Round 6
// 413.843 us; speedup vs baseline: 8.3891x; 2.5552x over previous
//
#include <hip/hip_runtime.h>
#include <hip/hip_bf16.h>

#define D_MODEL 2048
#define N_HEAD 32
#define N_KV_HEAD 8
#define N_REP 4
#define D_K 64
#define S_LEN 1024
#define B_SZ 2
#define M_ROWS (B_SZ * S_LEN)      // 2048
#define KV_DIM (N_KV_HEAD * D_K)   // 512

typedef __attribute__((ext_vector_type(8))) short short8;   // 8 bf16 (4 VGPRs)
typedef __attribute__((ext_vector_type(4))) float f32x4;

__device__ inline unsigned short f2bf(float f) {  // RNE fp32 -> bf16 bits
    union { float f; unsigned int u; } x{f};
    unsigned int r = x.u + 0x7fffu + ((x.u >> 16) & 1u);
    return (unsigned short)(r >> 16);
}
__device__ inline float bf2f(unsigned short b) {
    union { unsigned int u; float f; } x; x.u = ((unsigned int)b) << 16; return x.f;
}

// ---------------- transpose + cast: W[K,N] fp32 -> Wt[N,K] bf16 ----------------
__global__ void transpose_cast_kernel(const float* __restrict__ W,
                                      unsigned short* __restrict__ Wt,
                                      int K, int N) {
    __shared__ float tile[32][33];
    int n0 = blockIdx.x * 32, k0 = blockIdx.y * 32;
    int tx = threadIdx.x, ty = threadIdx.y;   // 32 x 8
#pragma unroll
    for (int r = 0; r < 4; r++)
        tile[ty * 4 + r][tx] = W[(size_t)(k0 + ty * 4 + r) * N + n0 + tx];
    __syncthreads();
#pragma unroll
    for (int r = 0; r < 4; r++)
        Wt[(size_t)(n0 + ty * 4 + r) * K + k0 + tx] = f2bf(tile[tx][ty * 4 + r]);
}

// ---------------- bf16 MFMA GEMM: C[M,N] = A[M,K] * Wt[N,K]^T + bias ----------
#define GSTRIDE 72
__global__ __launch_bounds__(256) void gemm_mfma_kernel(
        const float* __restrict__ A, const unsigned short* __restrict__ Wt,
        const float* __restrict__ bias, float* __restrict__ C,
        int M, int N, int K) {
    __shared__ unsigned short As[64 * GSTRIDE];
    __shared__ unsigned short Bs[64 * GSTRIDE];
    const int tid = threadIdx.x;
    const int lane = tid & 63;
    const int w = tid >> 6;
    const int wm = w >> 1, wn = w & 1;
    const int bm = blockIdx.y * 64, bn = blockIdx.x * 64;

    f32x4 acc[2][2];
#pragma unroll
    for (int i = 0; i < 2; i++)
#pragma unroll
        for (int j = 0; j < 2; j++) acc[i][j] = (f32x4){0.f, 0.f, 0.f, 0.f};

    const int qd = lane >> 4;
    const int lr = lane & 15;

    for (int k0 = 0; k0 < K; k0 += 64) {
        __syncthreads();
#pragma unroll
        for (int it = 0; it < 2; it++) {
            int c = it * 256 + tid;
            int row = c >> 3, k8 = (c & 7) * 8;
            const float4* src = (const float4*)(A + (size_t)(bm + row) * K + k0 + k8);
            float4 a0 = src[0], a1 = src[1];
            unsigned short* dst = &As[row * GSTRIDE + k8];
            dst[0] = f2bf(a0.x); dst[1] = f2bf(a0.y); dst[2] = f2bf(a0.z); dst[3] = f2bf(a0.w);
            dst[4] = f2bf(a1.x); dst[5] = f2bf(a1.y); dst[6] = f2bf(a1.z); dst[7] = f2bf(a1.w);
        }
#pragma unroll
        for (int it = 0; it < 2; it++) {
            int c = it * 256 + tid;
            int row = c >> 3, k8 = (c & 7) * 8;
            *(uint4*)&Bs[row * GSTRIDE + k8] =
                *(const uint4*)(Wt + (size_t)(bn + row) * K + k0 + k8);
        }
        __syncthreads();
#pragma unroll
        for (int ks = 0; ks < 2; ks++) {
            short8 af[2], bf[2];
#pragma unroll
            for (int i = 0; i < 2; i++)
                af[i] = *(const short8*)&As[(wm * 32 + i * 16 + lr) * GSTRIDE + ks * 32 + qd * 8];
#pragma unroll
            for (int j = 0; j < 2; j++)
                bf[j] = *(const short8*)&Bs[(wn * 32 + j * 16 + lr) * GSTRIDE + ks * 32 + qd * 8];
#pragma unroll
            for (int i = 0; i < 2; i++)
#pragma unroll
                for (int j = 0; j < 2; j++)
                    acc[i][j] = __builtin_amdgcn_mfma_f32_16x16x32_bf16(af[i], bf[j], acc[i][j], 0, 0, 0);
        }
    }
#pragma unroll
    for (int i = 0; i < 2; i++) {
#pragma unroll
        for (int j = 0; j < 2; j++) {
            int row0 = bm + wm * 32 + i * 16 + qd * 4;
            int col = bn + wn * 32 + j * 16 + lr;
            float bj = bias[col];
#pragma unroll
            for (int r = 0; r < 4; r++)
                C[(size_t)(row0 + r) * N + col] = acc[i][j][r] + bj;
        }
    }
}

// -------- RoPE + cast to bf16 (optionally scaled): t fp32 -> obf bf16 --------
__global__ void rope_cast_kernel(const float* __restrict__ t,
                                 unsigned short* __restrict__ obf,
                                 int n_heads, float scale) {
    int idx = blockIdx.x * blockDim.x + threadIdx.x;
    int total = M_ROWS * n_heads * 32;
    if (idx >= total) return;
    int i = idx & 31;
    int hh = (idx >> 5) % n_heads;
    int r = idx / (32 * n_heads);
    int s = r % S_LEN;
    float inv_freq = powf(10000.0f, -2.0f * (float)i / 64.0f);
    float ang = (float)s * inv_freq;
    float c = cosf(ang), sn = sinf(ang);
    const float* p = t + (size_t)r * (n_heads * D_K) + hh * D_K + 2 * i;
    float te = p[0], to = p[1];
    unsigned short* q = obf + (size_t)r * (n_heads * D_K) + hh * D_K + 2 * i;
    q[0] = f2bf((te * c - to * sn) * scale);
    q[1] = f2bf((te * sn + to * c) * scale);
}

// -------- plain fp32 -> bf16 cast (vectorized by 4) --------
__global__ void cast_bf_kernel(const float* __restrict__ src,
                               unsigned short* __restrict__ dst, int n4) {
    int idx = blockIdx.x * blockDim.x + threadIdx.x;
    if (idx >= n4) return;
    float4 v = ((const float4*)src)[idx];
    unsigned int lo = (unsigned int)f2bf(v.x) | ((unsigned int)f2bf(v.y) << 16);
    unsigned int hi = (unsigned int)f2bf(v.z) | ((unsigned int)f2bf(v.w) << 16);
    ((uint2*)dst)[idx] = make_uint2(lo, hi);
}

// ---------------- MFMA flash attention ----------------
// Block = 256 thr = 4 waves, one (b,h); processes q-tiles blockIdx.x and
// 15-blockIdx.x (64 rows each) -> 17 K-tiles per block (balanced causal).
// Wave owns 16 q-rows. Ks[key][dim] (B^T layout), Vt[dim][key] (transposed),
// Ps[row][key] for the P round-trip (wave-private rows; no extra barrier).
#define AST 72
__global__ __launch_bounds__(256) void attn_mfma_kernel(
        const unsigned short* __restrict__ qbf,   // [M_ROWS][D_MODEL], pre-scaled
        const unsigned short* __restrict__ kbf,   // [M_ROWS][KV_DIM], RoPE'd
        const unsigned short* __restrict__ vbf,   // [M_ROWS][KV_DIM]
        float* __restrict__ o) {                  // [M_ROWS][D_MODEL] fp32
    __shared__ unsigned short Ks[64 * AST];
    __shared__ unsigned short Vt[64 * AST];
    __shared__ unsigned short Ps[64 * AST];
    const int tid = threadIdx.x;
    const int w = tid >> 6, lane = tid & 63;
    const int lr = lane & 15, quad = lane >> 4;
    const int h = blockIdx.y, b = blockIdx.z;
    const int kvh = h >> 2;
    const unsigned short* kb = kbf + (size_t)b * S_LEN * KV_DIM + kvh * D_K;
    const unsigned short* vb = vbf + (size_t)b * S_LEN * KV_DIM + kvh * D_K;

    for (int hp = 0; hp < 2; hp++) {
        const int qt = (hp == 0) ? (int)blockIdx.x : 15 - (int)blockIdx.x;
        const int q0 = qt * 64;
        // Q A-frags: rows q0 + w*16 + lr, dims ks*32 + quad*8
        short8 aq[2];
        {
            const unsigned short* qp = qbf + (size_t)(b * S_LEN + q0 + w * 16 + lr) * D_MODEL
                                       + h * D_K + quad * 8;
            aq[0] = *(const short8*)qp;
            aq[1] = *(const short8*)(qp + 32);
        }
        f32x4 oacc[4];
#pragma unroll
        for (int cf = 0; cf < 4; cf++) oacc[cf] = (f32x4){0.f, 0.f, 0.f, 0.f};
        float mrow[4] = {-1e30f, -1e30f, -1e30f, -1e30f};
        float lrow[4] = {0.f, 0.f, 0.f, 0.f};

        const int ntiles = qt + 1;
        for (int t = 0; t < ntiles; t++) {
            const int j0 = t * 64;
            __syncthreads();
            // stage K tile [64 keys][64 dims]
#pragma unroll
            for (int it = 0; it < 2; it++) {
                int f = it * 256 + tid;
                int key = f >> 3, d8 = (f & 7) * 8;
                *(uint4*)&Ks[key * AST + d8] =
                    *(const uint4*)(kb + (size_t)(j0 + key) * KV_DIM + d8);
            }
            // stage V transposed: Vt[dim][key]
            {
                int key = tid & 63, dq = tid >> 6;
                unsigned short tmp[16];
                const uint4* vp = (const uint4*)(vb + (size_t)(j0 + key) * KV_DIM + dq * 16);
                *(uint4*)tmp = vp[0];
                *(uint4*)(tmp + 8) = vp[1];
#pragma unroll
                for (int i = 0; i < 16; i++) Vt[(dq * 16 + i) * AST + key] = tmp[i];
            }
            __syncthreads();
            // S = Q K^T  (16 rows x 64 keys per wave)
            f32x4 s[4];
#pragma unroll
            for (int cf = 0; cf < 4; cf++) s[cf] = (f32x4){0.f, 0.f, 0.f, 0.f};
#pragma unroll
            for (int ks = 0; ks < 2; ks++) {
#pragma unroll
                for (int cf = 0; cf < 4; cf++) {
                    short8 bk = *(const short8*)&Ks[(cf * 16 + lr) * AST + ks * 32 + quad * 8];
                    s[cf] = __builtin_amdgcn_mfma_f32_16x16x32_bf16(aq[ks], bk, s[cf], 0, 0, 0);
                }
            }
            // causal mask: only the diagonal tile needs it
            if (j0 == q0) {
#pragma unroll
                for (int cf = 0; cf < 4; cf++) {
                    int key = cf * 16 + lr;
#pragma unroll
                    for (int r = 0; r < 4; r++) {
                        int row = w * 16 + quad * 4 + r;
                        if (key > row) s[cf][r] = -1e30f;
                    }
                }
            }
            // online softmax per row; P -> bf16 -> LDS; l from rounded p
            float corr[4];
#pragma unroll
            for (int r = 0; r < 4; r++) {
                float rm = fmaxf(fmaxf(s[0][r], s[1][r]), fmaxf(s[2][r], s[3][r]));
                rm = fmaxf(rm, __shfl_xor(rm, 1));
                rm = fmaxf(rm, __shfl_xor(rm, 2));
                rm = fmaxf(rm, __shfl_xor(rm, 4));
                rm = fmaxf(rm, __shfl_xor(rm, 8));
                float mn = fmaxf(mrow[r], rm);
                corr[r] = __expf(mrow[r] - mn);
                mrow[r] = mn;
                float rs = 0.f;
#pragma unroll
                for (int cf = 0; cf < 4; cf++) {
                    float p = __expf(s[cf][r] - mn);
                    unsigned short pb = f2bf(p);
                    Ps[(w * 16 + quad * 4 + r) * AST + cf * 16 + lr] = pb;
                    rs += bf2f(pb);
                }
                rs += __shfl_xor(rs, 1);
                rs += __shfl_xor(rs, 2);
                rs += __shfl_xor(rs, 4);
                rs += __shfl_xor(rs, 8);
                lrow[r] = lrow[r] * corr[r] + rs;
            }
#pragma unroll
            for (int cf = 0; cf < 4; cf++)
#pragma unroll
                for (int r = 0; r < 4; r++) oacc[cf][r] *= corr[r];
            // O += P V   (A-frags from wave-private Ps rows)
#pragma unroll
            for (int ks = 0; ks < 2; ks++) {
                short8 ap = *(const short8*)&Ps[(w * 16 + lr) * AST + ks * 32 + quad * 8];
#pragma unroll
                for (int cf = 0; cf < 4; cf++) {
                    short8 bv = *(const short8*)&Vt[(cf * 16 + lr) * AST + ks * 32 + quad * 8];
                    oacc[cf] = __builtin_amdgcn_mfma_f32_16x16x32_bf16(ap, bv, oacc[cf], 0, 0, 0);
                }
            }
        }
        // write O (fp32)
#pragma unroll
        for (int r = 0; r < 4; r++) {
            float inv = 1.f / lrow[r];
            int row = b * S_LEN + q0 + w * 16 + quad * 4 + r;
#pragma unroll
            for (int cf = 0; cf < 4; cf++)
                o[(size_t)row * D_MODEL + h * D_K + cf * 16 + lr] = oacc[cf][r] * inv;
        }
    }
}

extern "C" void kernel_launch(void* const* d_in, const int* in_sizes, int n_in,
                              void* d_out, int out_size, void* d_ws, size_t ws_size,
                              hipStream_t stream) {
    const float* x  = (const float*)d_in[0];
    const float* Wq = (const float*)d_in[1];
    const float* bq = (const float*)d_in[2];
    const float* Wk = (const float*)d_in[3];
    const float* bk = (const float*)d_in[4];
    const float* Wv = (const float*)d_in[5];
    const float* bv = (const float*)d_in[6];
    const float* Wo = (const float*)d_in[7];
    const float* bo = (const float*)d_in[8];
    float* out = (float*)d_out;

    // ws: qws 16MB | kws 4MB | vws 4MB | Wt 8MB | qbf 8MB | kbf 2MB | vbf 2MB = 44MB
    float* qws = (float*)d_ws;
    float* kws = qws + (size_t)M_ROWS * D_MODEL;
    float* vws = kws + (size_t)M_ROWS * KV_DIM;
    unsigned short* Wt  = (unsigned short*)(vws + (size_t)M_ROWS * KV_DIM);
    unsigned short* qbf = Wt + (size_t)D_MODEL * D_MODEL;
    unsigned short* kbf = qbf + (size_t)M_ROWS * D_MODEL;
    unsigned short* vbf = kbf + (size_t)M_ROWS * KV_DIM;
    float* aws = qws;  // attention O output reuses qws (qws fully consumed by then)

    dim3 tb(32, 8);
    dim3 gb(256);

    // Q proj
    transpose_cast_kernel<<<dim3(D_MODEL / 32, D_MODEL / 32), tb, 0, stream>>>(Wq, Wt, D_MODEL, D_MODEL);
    gemm_mfma_kernel<<<dim3(D_MODEL / 64, M_ROWS / 64), gb, 0, stream>>>(x, Wt, bq, qws, M_ROWS, D_MODEL, D_MODEL);
    // K proj
    transpose_cast_kernel<<<dim3(KV_DIM / 32, D_MODEL / 32), tb, 0, stream>>>(Wk, Wt, D_MODEL, KV_DIM);
    gemm_mfma_kernel<<<dim3(KV_DIM / 64, M_ROWS / 64), gb, 0, stream>>>(x, Wt, bk, kws, M_ROWS, KV_DIM, D_MODEL);
    // V proj
    transpose_cast_kernel<<<dim3(KV_DIM / 32, D_MODEL / 32), tb, 0, stream>>>(Wv, Wt, D_MODEL, KV_DIM);
    gemm_mfma_kernel<<<dim3(KV_DIM / 64, M_ROWS / 64), gb, 0, stream>>>(x, Wt, bv, vws, M_ROWS, KV_DIM, D_MODEL);
    // RoPE+cast Q (scaled 1/sqrt(64)), RoPE+cast K, cast V
    rope_cast_kernel<<<(M_ROWS * N_HEAD * 32 + 255) / 256, gb, 0, stream>>>(qws, qbf, N_HEAD, 0.125f);
    rope_cast_kernel<<<(M_ROWS * N_KV_HEAD * 32 + 255) / 256, gb, 0, stream>>>(kws, kbf, N_KV_HEAD, 1.0f);
    cast_bf_kernel<<<(M_ROWS * KV_DIM / 4 + 255) / 256, gb, 0, stream>>>(vws, vbf, M_ROWS * KV_DIM / 4);
    // MFMA flash attention
    attn_mfma_kernel<<<dim3(8, N_HEAD, B_SZ), gb, 0, stream>>>(qbf, kbf, vbf, aws);
    // O proj
    transpose_cast_kernel<<<dim3(D_MODEL / 32, D_MODEL / 32), tb, 0, stream>>>(Wo, Wt, D_MODEL, D_MODEL);
    gemm_mfma_kernel<<<dim3(D_MODEL / 64, M_ROWS / 64), gb, 0, stream>>>(aws, Wt, bo, out, M_ROWS, D_MODEL, D_MODEL);
}

// Round 7
// 266.489 us; speedup vs baseline: 13.0279x; 1.5530x over previous
//
#include <hip/hip_runtime.h>
#include <hip/hip_bf16.h>

#define D_MODEL 2048
#define N_HEAD 32
#define N_KV_HEAD 8
#define N_REP 4
#define D_K 64
#define S_LEN 1024
#define B_SZ 2
#define M_ROWS (B_SZ * S_LEN)      // 2048
#define KV_DIM (N_KV_HEAD * D_K)   // 512
#define QKV_N 3072                 // 2048 q | 512 k | 512 v
#define KOFF 2048
#define VOFF 2560

typedef __attribute__((ext_vector_type(8))) short short8;   // 8 bf16 (4 VGPRs)
typedef __attribute__((ext_vector_type(4))) float f32x4;

__device__ inline unsigned short f2bf(float f) {  // RNE fp32 -> bf16 bits
    union { float f; unsigned int u; } x{f};
    unsigned int r = x.u + 0x7fffu + ((x.u >> 16) & 1u);
    return (unsigned short)(r >> 16);
}
__device__ inline float bf2f(unsigned short b) {
    union { unsigned int u; float f; } x; x.u = ((unsigned int)b) << 16; return x.f;
}
__device__ inline void store_c(float* p, float v) { *p = v; }
__device__ inline void store_c(unsigned short* p, float v) { *p = f2bf(v); }

// async 16B global -> LDS (global_load_lds_dwordx4)
__device__ inline void load_lds16(const unsigned short* g, unsigned short* l) {
    __builtin_amdgcn_global_load_lds(
        (const __attribute__((address_space(1))) unsigned int*)g,
        (__attribute__((address_space(3))) unsigned int*)l, 16, 0, 0);
}

// ---------------- transpose + cast: W[K,N] fp32 -> Wt[N,K] bf16 ----------------
__global__ void transpose_cast_kernel(const float* __restrict__ W,
                                      unsigned short* __restrict__ Wt,
                                      int K, int N) {
    __shared__ float tile[32][33];
    int n0 = blockIdx.x * 32, k0 = blockIdx.y * 32;
    int tx = threadIdx.x, ty = threadIdx.y;   // 32 x 8
#pragma unroll
    for (int r = 0; r < 4; r++)
        tile[ty * 4 + r][tx] = W[(size_t)(k0 + ty * 4 + r) * N + n0 + tx];
    __syncthreads();
#pragma unroll
    for (int r = 0; r < 4; r++)
        Wt[(size_t)(n0 + ty * 4 + r) * K + k0 + tx] = f2bf(tile[tx][ty * 4 + r]);
}

// -------- fp32 -> bf16 cast (vectorized by 4) --------
__global__ void cast_bf_kernel(const float* __restrict__ src,
                               unsigned short* __restrict__ dst, int n4) {
    int idx = blockIdx.x * blockDim.x + threadIdx.x;
    if (idx >= n4) return;
    float4 v = ((const float4*)src)[idx];
    unsigned int lo = (unsigned int)f2bf(v.x) | ((unsigned int)f2bf(v.y) << 16);
    unsigned int hi = (unsigned int)f2bf(v.z) | ((unsigned int)f2bf(v.w) << 16);
    ((uint2*)dst)[idx] = make_uint2(lo, hi);
}

// -------- concat bias q|k|v (fp32) --------
__global__ void concat_bias_kernel(const float* __restrict__ bq, const float* __restrict__ bk,
                                   const float* __restrict__ bv, float* __restrict__ dst) {
    int i = blockIdx.x * blockDim.x + threadIdx.x;
    if (i >= QKV_N) return;
    dst[i] = (i < KOFF) ? bq[i] : (i < VOFF) ? bk[i - KOFF] : bv[i - VOFF];
}

// ---------------- m97-style bf16 GEMM: C[M,N] = A[M,K] * Bt[N,K]^T + bias ------
// 128x128 tile, BK=64, 256 thr = 4 waves (2x2), wave = 64x64 (4x4 16x16x32 frags).
// LDS staged via global_load_lds w=16; XOR chunk swizzle (absorbed in global addr)
// makes frag ds_read_b128 conflict-free. No padding (global_load_lds requires).
template <typename TC>
__global__ __launch_bounds__(256) void gemm_bf16_kernel(
        const unsigned short* __restrict__ A,   // [M][K] bf16
        const unsigned short* __restrict__ Bt,  // [N][K] bf16
        const float* __restrict__ bias,
        TC* __restrict__ C, int M, int N, int K) {
    __shared__ unsigned short As[128 * 64];
    __shared__ unsigned short Bs[128 * 64];
    const int tid = threadIdx.x, lane = tid & 63;
    const int w = tid >> 6, wm = w >> 1, wn = w & 1;
    const int quad = lane >> 4, lr = lane & 15;
    const int bm = blockIdx.y * 128, bn = blockIdx.x * 128;

    f32x4 acc[4][4];
#pragma unroll
    for (int i = 0; i < 4; i++)
#pragma unroll
        for (int j = 0; j < 4; j++) acc[i][j] = (f32x4){0.f, 0.f, 0.f, 0.f};

    for (int k0 = 0; k0 < K; k0 += 64) {
        __syncthreads();
        // 1024 16B-chunks per tile; slot -> (row, swizzled chunk)
#pragma unroll
        for (int it = 0; it < 4; it++) {
            int slot = it * 256 + tid;
            int row = slot >> 3;
            int qc = (slot & 7) ^ (row & 7);
            load_lds16(A  + (size_t)(bm + row) * K + k0 + qc * 8, &As[slot * 8]);
            load_lds16(Bt + (size_t)(bn + row) * K + k0 + qc * 8, &Bs[slot * 8]);
        }
        __syncthreads();
#pragma unroll
        for (int ks = 0; ks < 2; ks++) {
            short8 af[4], bf[4];
#pragma unroll
            for (int i = 0; i < 4; i++) {
                int row = wm * 64 + i * 16 + lr;
                af[i] = *(const short8*)&As[(row * 8 + ((ks * 4 + quad) ^ (lr & 7))) * 8];
            }
#pragma unroll
            for (int j = 0; j < 4; j++) {
                int row = wn * 64 + j * 16 + lr;
                bf[j] = *(const short8*)&Bs[(row * 8 + ((ks * 4 + quad) ^ (lr & 7))) * 8];
            }
#pragma unroll
            for (int i = 0; i < 4; i++)
#pragma unroll
                for (int j = 0; j < 4; j++)
                    acc[i][j] = __builtin_amdgcn_mfma_f32_16x16x32_bf16(af[i], bf[j], acc[i][j], 0, 0, 0);
        }
    }
    // epilogue: C/D layout col = lane&15, row = quad*4 + reg
#pragma unroll
    for (int i = 0; i < 4; i++) {
#pragma unroll
        for (int j = 0; j < 4; j++) {
            int col = bn + wn * 64 + j * 16 + lr;
            int row0 = bm + wm * 64 + i * 16 + quad * 4;
            float bj = bias[col];
#pragma unroll
            for (int r = 0; r < 4; r++)
                store_c(&C[(size_t)(row0 + r) * N + col], acc[i][j][r] + bj);
        }
    }
}

// -------- RoPE in-place on bf16 QKV buffer (q cols scaled) --------
__global__ void rope_bf_kernel(unsigned short* __restrict__ t, int col_off,
                               int n_heads, float scale) {
    int idx = blockIdx.x * blockDim.x + threadIdx.x;
    int total = M_ROWS * n_heads * 32;
    if (idx >= total) return;
    int i = idx & 31;
    int hh = (idx >> 5) % n_heads;
    int r = idx / (32 * n_heads);
    int s = r % S_LEN;
    float inv_freq = powf(10000.0f, -2.0f * (float)i / 64.0f);
    float ang = (float)s * inv_freq;
    float c = cosf(ang), sn = sinf(ang);
    unsigned short* p = t + (size_t)r * QKV_N + col_off + hh * D_K + 2 * i;
    float te = bf2f(p[0]), to = bf2f(p[1]);
    p[0] = f2bf((te * c - to * sn) * scale);
    p[1] = f2bf((te * sn + to * c) * scale);
}

// ---------------- MFMA flash attention (reads strided QKV buffer) ----------------
#define AST 72
__global__ __launch_bounds__(256) void attn_mfma_kernel(
        const unsigned short* __restrict__ qkv,   // [M_ROWS][QKV_N] bf16, q pre-scaled
        unsigned short* __restrict__ obf) {       // [M_ROWS][D_MODEL] bf16
    __shared__ unsigned short Ks[64 * AST];
    __shared__ unsigned short Vt[64 * AST];
    __shared__ unsigned short Ps[64 * AST];
    const int tid = threadIdx.x;
    const int w = tid >> 6, lane = tid & 63;
    const int lr = lane & 15, quad = lane >> 4;
    const int h = blockIdx.y, b = blockIdx.z;
    const int kvh = h >> 2;
    const unsigned short* kb = qkv + (size_t)(b * S_LEN) * QKV_N + KOFF + kvh * D_K;
    const unsigned short* vb = qkv + (size_t)(b * S_LEN) * QKV_N + VOFF + kvh * D_K;

    for (int hp = 0; hp < 2; hp++) {
        const int qt = (hp == 0) ? (int)blockIdx.x : 15 - (int)blockIdx.x;
        const int q0 = qt * 64;
        short8 aq[2];
        {
            const unsigned short* qp = qkv + (size_t)(b * S_LEN + q0 + w * 16 + lr) * QKV_N
                                       + h * D_K + quad * 8;
            aq[0] = *(const short8*)qp;
            aq[1] = *(const short8*)(qp + 32);
        }
        f32x4 oacc[4];
#pragma unroll
        for (int cf = 0; cf < 4; cf++) oacc[cf] = (f32x4){0.f, 0.f, 0.f, 0.f};
        float mrow[4] = {-1e30f, -1e30f, -1e30f, -1e30f};
        float lrow[4] = {0.f, 0.f, 0.f, 0.f};

        const int ntiles = qt + 1;
        for (int t = 0; t < ntiles; t++) {
            const int j0 = t * 64;
            __syncthreads();
#pragma unroll
            for (int it = 0; it < 2; it++) {
                int f = it * 256 + tid;
                int key = f >> 3, d8 = (f & 7) * 8;
                *(uint4*)&Ks[key * AST + d8] =
                    *(const uint4*)(kb + (size_t)(j0 + key) * QKV_N + d8);
            }
            {
                int key = tid & 63, dq = tid >> 6;
                unsigned short tmp[16];
                const uint4* vp = (const uint4*)(vb + (size_t)(j0 + key) * QKV_N + dq * 16);
                *(uint4*)tmp = vp[0];
                *(uint4*)(tmp + 8) = vp[1];
#pragma unroll
                for (int i = 0; i < 16; i++) Vt[(dq * 16 + i) * AST + key] = tmp[i];
            }
            __syncthreads();
            f32x4 s[4];
#pragma unroll
            for (int cf = 0; cf < 4; cf++) s[cf] = (f32x4){0.f, 0.f, 0.f, 0.f};
#pragma unroll
            for (int ks = 0; ks < 2; ks++) {
#pragma unroll
                for (int cf = 0; cf < 4; cf++) {
                    short8 bk = *(const short8*)&Ks[(cf * 16 + lr) * AST + ks * 32 + quad * 8];
                    s[cf] = __builtin_amdgcn_mfma_f32_16x16x32_bf16(aq[ks], bk, s[cf], 0, 0, 0);
                }
            }
            if (j0 == q0) {
#pragma unroll
                for (int cf = 0; cf < 4; cf++) {
                    int key = cf * 16 + lr;
#pragma unroll
                    for (int r = 0; r < 4; r++) {
                        int row = w * 16 + quad * 4 + r;
                        if (key > row) s[cf][r] = -1e30f;
                    }
                }
            }
            float corr[4];
#pragma unroll
            for (int r = 0; r < 4; r++) {
                float rm = fmaxf(fmaxf(s[0][r], s[1][r]), fmaxf(s[2][r], s[3][r]));
                rm = fmaxf(rm, __shfl_xor(rm, 1));
                rm = fmaxf(rm, __shfl_xor(rm, 2));
                rm = fmaxf(rm, __shfl_xor(rm, 4));
                rm = fmaxf(rm, __shfl_xor(rm, 8));
                float mn = fmaxf(mrow[r], rm);
                corr[r] = __expf(mrow[r] - mn);
                mrow[r] = mn;
                float rs = 0.f;
#pragma unroll
                for (int cf = 0; cf < 4; cf++) {
                    float p = __expf(s[cf][r] - mn);
                    unsigned short pb = f2bf(p);
                    Ps[(w * 16 + quad * 4 + r) * AST + cf * 16 + lr] = pb;
                    rs += bf2f(pb);
                }
                rs += __shfl_xor(rs, 1);
                rs += __shfl_xor(rs, 2);
                rs += __shfl_xor(rs, 4);
                rs += __shfl_xor(rs, 8);
                lrow[r] = lrow[r] * corr[r] + rs;
            }
#pragma unroll
            for (int cf = 0; cf < 4; cf++)
#pragma unroll
                for (int r = 0; r < 4; r++) oacc[cf][r] *= corr[r];
#pragma unroll
            for (int ks = 0; ks < 2; ks++) {
                short8 ap = *(const short8*)&Ps[(w * 16 + lr) * AST + ks * 32 + quad * 8];
#pragma unroll
                for (int cf = 0; cf < 4; cf++) {
                    short8 bv = *(const short8*)&Vt[(cf * 16 + lr) * AST + ks * 32 + quad * 8];
                    oacc[cf] = __builtin_amdgcn_mfma_f32_16x16x32_bf16(ap, bv, oacc[cf], 0, 0, 0);
                }
            }
        }
#pragma unroll
        for (int r = 0; r < 4; r++) {
            float inv = 1.f / lrow[r];
            int row = b * S_LEN + q0 + w * 16 + quad * 4 + r;
#pragma unroll
            for (int cf = 0; cf < 4; cf++)
                obf[(size_t)row * D_MODEL + h * D_K + cf * 16 + lr] = f2bf(oacc[cf][r] * inv);
        }
    }
}

extern "C" void kernel_launch(void* const* d_in, const int* in_sizes, int n_in,
                              void* d_out, int out_size, void* d_ws, size_t ws_size,
                              hipStream_t stream) {
    const float* x  = (const float*)d_in[0];
    const float* Wq = (const float*)d_in[1];
    const float* bq = (const float*)d_in[2];
    const float* Wk = (const float*)d_in[3];
    const float* bk = (const float*)d_in[4];
    const float* Wv = (const float*)d_in[5];
    const float* bv = (const float*)d_in[6];
    const float* Wo = (const float*)d_in[7];
    const float* bo = (const float*)d_in[8];
    float* out = (float*)d_out;

    // ws (bf16 elems): xbf/obf 8MB | WtQKV 12MB | WtO 8MB | qkv 12MB | bias 12KB = 40MB
    unsigned short* xbf   = (unsigned short*)d_ws;                       // [2048][2048]
    unsigned short* WtQKV = xbf + (size_t)M_ROWS * D_MODEL;              // [3072][2048]
    unsigned short* WtO   = WtQKV + (size_t)QKV_N * D_MODEL;             // [2048][2048]
    unsigned short* qkv   = WtO + (size_t)D_MODEL * D_MODEL;             // [2048][3072]
    float* bias_qkv       = (float*)(qkv + (size_t)M_ROWS * QKV_N);      // [3072]
    unsigned short* obf   = xbf;  // xbf consumed by QKV GEMM before attn writes

    dim3 tb(32, 8);
    dim3 gb(256);

    // prep: cast x, transpose weights, concat bias
    cast_bf_kernel<<<(M_ROWS * D_MODEL / 4 + 255) / 256, gb, 0, stream>>>(x, xbf, M_ROWS * D_MODEL / 4);
    transpose_cast_kernel<<<dim3(D_MODEL / 32, D_MODEL / 32), tb, 0, stream>>>(Wq, WtQKV, D_MODEL, D_MODEL);
    transpose_cast_kernel<<<dim3(KV_DIM / 32, D_MODEL / 32), tb, 0, stream>>>(Wk, WtQKV + (size_t)KOFF * D_MODEL, D_MODEL, KV_DIM);
    transpose_cast_kernel<<<dim3(KV_DIM / 32, D_MODEL / 32), tb, 0, stream>>>(Wv, WtQKV + (size_t)VOFF * D_MODEL, D_MODEL, KV_DIM);
    concat_bias_kernel<<<(QKV_N + 255) / 256, gb, 0, stream>>>(bq, bk, bv, bias_qkv);
    // fused QKV projection (bf16 out)
    gemm_bf16_kernel<unsigned short><<<dim3(QKV_N / 128, M_ROWS / 128), gb, 0, stream>>>(
        xbf, WtQKV, bias_qkv, qkv, M_ROWS, QKV_N, D_MODEL);
    // RoPE in-place (q scaled by 1/sqrt(64))
    rope_bf_kernel<<<(M_ROWS * N_HEAD * 32 + 255) / 256, gb, 0, stream>>>(qkv, 0, N_HEAD, 0.125f);
    rope_bf_kernel<<<(M_ROWS * N_KV_HEAD * 32 + 255) / 256, gb, 0, stream>>>(qkv, KOFF, N_KV_HEAD, 1.0f);
    // attention
    attn_mfma_kernel<<<dim3(8, N_HEAD, B_SZ), gb, 0, stream>>>(qkv, obf);
    // O projection (fp32 out)
    transpose_cast_kernel<<<dim3(D_MODEL / 32, D_MODEL / 32), tb, 0, stream>>>(Wo, WtO, D_MODEL, D_MODEL);
    gemm_bf16_kernel<float><<<dim3(D_MODEL / 128, M_ROWS / 128), gb, 0, stream>>>(
        obf, WtO, bo, out, M_ROWS, D_MODEL, D_MODEL);
}

// Round 9
// 242.418 us; speedup vs baseline: 14.3214x; 1.0993x over previous
//
#include <hip/hip_runtime.h>
#include <hip/hip_bf16.h>

#define D_MODEL 2048
#define N_HEAD 32
#define N_KV_HEAD 8
#define N_REP 4
#define D_K 64
#define S_LEN 1024
#define B_SZ 2
#define M_ROWS (B_SZ * S_LEN)      // 2048
#define KV_DIM (N_KV_HEAD * D_K)   // 512
#define QKV_N 3072                 // 2048 q | 512 k | 512 v
#define KOFF 2048
#define VOFF 2560
#define LOG2E 1.44269504088896f

typedef __attribute__((ext_vector_type(8))) short short8;   // 8 bf16 (4 VGPRs)
typedef __attribute__((ext_vector_type(4))) float f32x4;

#define EXP2F(x) __builtin_amdgcn_exp2f(x)   // v_exp_f32 (2^x native)

__device__ inline unsigned short f2bf(float f) {  // RNE fp32 -> bf16 bits
    union { float f; unsigned int u; } x{f};
    unsigned int r = x.u + 0x7fffu + ((x.u >> 16) & 1u);
    return (unsigned short)(r >> 16);
}
__device__ inline float bf2f(unsigned short b) {
    union { unsigned int u; float f; } x; x.u = ((unsigned int)b) << 16; return x.f;
}
__device__ inline void store_c(float* p, float v) { *p = v; }
__device__ inline void store_c(unsigned short* p, float v) { *p = f2bf(v); }

// async 16B global -> LDS (global_load_lds_dwordx4)
__device__ inline void load_lds16(const unsigned short* g, unsigned short* l) {
    __builtin_amdgcn_global_load_lds(
        (const __attribute__((address_space(1))) unsigned int*)g,
        (__attribute__((address_space(3))) unsigned int*)l, 16, 0, 0);
}

// ---------------- transpose + cast: W[K,N] fp32 -> Wt[N,K] bf16 ----------------
__global__ void transpose_cast_kernel(const float* __restrict__ W,
                                      unsigned short* __restrict__ Wt,
                                      int K, int N) {
    __shared__ float tile[32][33];
    int n0 = blockIdx.x * 32, k0 = blockIdx.y * 32;
    int tx = threadIdx.x, ty = threadIdx.y;   // 32 x 8
#pragma unroll
    for (int r = 0; r < 4; r++)
        tile[ty * 4 + r][tx] = W[(size_t)(k0 + ty * 4 + r) * N + n0 + tx];
    __syncthreads();
#pragma unroll
    for (int r = 0; r < 4; r++)
        Wt[(size_t)(n0 + ty * 4 + r) * K + k0 + tx] = f2bf(tile[tx][ty * 4 + r]);
}

// -------- fp32 -> bf16 cast (vectorized by 4) --------
__global__ void cast_bf_kernel(const float* __restrict__ src,
                               unsigned short* __restrict__ dst, int n4) {
    int idx = blockIdx.x * blockDim.x + threadIdx.x;
    if (idx >= n4) return;
    float4 v = ((const float4*)src)[idx];
    unsigned int lo = (unsigned int)f2bf(v.x) | ((unsigned int)f2bf(v.y) << 16);
    unsigned int hi = (unsigned int)f2bf(v.z) | ((unsigned int)f2bf(v.w) << 16);
    ((uint2*)dst)[idx] = make_uint2(lo, hi);
}

// -------- concat bias q|k|v (fp32) --------
__global__ void concat_bias_kernel(const float* __restrict__ bq, const float* __restrict__ bk,
                                   const float* __restrict__ bv, float* __restrict__ dst) {
    int i = blockIdx.x * blockDim.x + threadIdx.x;
    if (i >= QKV_N) return;
    dst[i] = (i < KOFF) ? bq[i] : (i < VOFF) ? bk[i - KOFF] : bv[i - VOFF];
}

// ---------------- bf16 GEMM: C[M,N] = A[M,K] * Bt[N,K]^T + bias ------
// BM=128, BN=64, BK=64, 256 thr = 4 waves (2x2); wave = 64x32 (4x2 16x16x32 frags).
// global_load_lds w=16 staging, XOR chunk swizzle absorbed into global address.
template <typename TC>
__global__ __launch_bounds__(256) void gemm_bf16_kernel(
        const unsigned short* __restrict__ A,   // [M][K] bf16
        const unsigned short* __restrict__ Bt,  // [N][K] bf16
        const float* __restrict__ bias,
        TC* __restrict__ C, int M, int N, int K) {
    __shared__ unsigned short As[128 * 64];
    __shared__ unsigned short Bs[64 * 64];
    const int tid = threadIdx.x, lane = tid & 63;
    const int w = tid >> 6, wm = w >> 1, wn = w & 1;
    const int quad = lane >> 4, lr = lane & 15;
    const int bm = blockIdx.y * 128, bn = blockIdx.x * 64;

    f32x4 acc[4][2];
#pragma unroll
    for (int i = 0; i < 4; i++)
#pragma unroll
        for (int j = 0; j < 2; j++) acc[i][j] = (f32x4){0.f, 0.f, 0.f, 0.f};

    for (int k0 = 0; k0 < K; k0 += 64) {
        __syncthreads();
        // A: 128 rows x 8 chunks = 1024 slots; B: 64 rows x 8 = 512 slots
#pragma unroll
        for (int it = 0; it < 4; it++) {
            int slot = it * 256 + tid;
            int row = slot >> 3;
            int qc = (slot & 7) ^ (row & 7);
            load_lds16(A + (size_t)(bm + row) * K + k0 + qc * 8, &As[slot * 8]);
        }
#pragma unroll
        for (int it = 0; it < 2; it++) {
            int slot = it * 256 + tid;
            int row = slot >> 3;
            int qc = (slot & 7) ^ (row & 7);
            load_lds16(Bt + (size_t)(bn + row) * K + k0 + qc * 8, &Bs[slot * 8]);
        }
        __syncthreads();
#pragma unroll
        for (int ks = 0; ks < 2; ks++) {
            short8 af[4], bf[2];
#pragma unroll
            for (int i = 0; i < 4; i++) {
                int row = wm * 64 + i * 16 + lr;
                af[i] = *(const short8*)&As[(row * 8 + ((ks * 4 + quad) ^ (lr & 7))) * 8];
            }
#pragma unroll
            for (int j = 0; j < 2; j++) {
                int row = wn * 32 + j * 16 + lr;
                bf[j] = *(const short8*)&Bs[(row * 8 + ((ks * 4 + quad) ^ (lr & 7))) * 8];
            }
#pragma unroll
            for (int i = 0; i < 4; i++)
#pragma unroll
                for (int j = 0; j < 2; j++)
                    acc[i][j] = __builtin_amdgcn_mfma_f32_16x16x32_bf16(af[i], bf[j], acc[i][j], 0, 0, 0);
        }
    }
#pragma unroll
    for (int i = 0; i < 4; i++) {
#pragma unroll
        for (int j = 0; j < 2; j++) {
            int col = bn + wn * 32 + j * 16 + lr;
            int row0 = bm + wm * 64 + i * 16 + quad * 4;
            float bj = bias[col];
#pragma unroll
            for (int r = 0; r < 4; r++)
                store_c(&C[(size_t)(row0 + r) * N + col], acc[i][j][r] + bj);
        }
    }
}

// -------- fused RoPE in-place on bf16 QKV buffer (q scaled by 0.125*log2e) -----
__global__ void rope_bf_kernel(unsigned short* __restrict__ t) {
    const int QI = M_ROWS * N_HEAD * 32;          // q items
    const int TOT = QI + M_ROWS * N_KV_HEAD * 32; // + k items
    int idx = blockIdx.x * blockDim.x + threadIdx.x;
    if (idx >= TOT) return;
    int col_off, n_heads;
    float scale;
    if (idx < QI) { col_off = 0; n_heads = N_HEAD; scale = 0.125f * LOG2E; }
    else { idx -= QI; col_off = KOFF; n_heads = N_KV_HEAD; scale = 1.0f; }
    int i = idx & 31;
    int hh = (idx >> 5) % n_heads;
    int r = idx / (32 * n_heads);
    int s = r % S_LEN;
    float inv_freq = powf(10000.0f, -2.0f * (float)i / 64.0f);
    float ang = (float)s * inv_freq;
    float c = cosf(ang), sn = sinf(ang);
    unsigned short* p = t + (size_t)r * QKV_N + col_off + hh * D_K + 2 * i;
    float te = bf2f(p[0]), to = bf2f(p[1]);
    p[0] = f2bf((te * c - to * sn) * scale);
    p[1] = f2bf((te * sn + to * c) * scale);
}

// ---------------- MFMA flash attention ----------------
// Block = 256 thr = 4 waves, one (b,h); q-tiles qtA=bx (0..7) and qtB=15-bx share
// each staged K/V tile: staging phases = qtB+1 instead of qtA+qtB+2.
// Scores arrive in log2 domain (q pre-scaled by 0.125*log2e) -> exp2 softmax.
#define AST 72
__device__ __forceinline__ void attn_tile(
        int w, int quad, int lr, bool diag,
        const unsigned short* Ks, const unsigned short* Vt, unsigned short* Ps,
        const short8* aq, f32x4* oacc, float* mrow, float* lrow) {
    f32x4 s[4];
#pragma unroll
    for (int cf = 0; cf < 4; cf++) s[cf] = (f32x4){0.f, 0.f, 0.f, 0.f};
#pragma unroll
    for (int ks = 0; ks < 2; ks++) {
#pragma unroll
        for (int cf = 0; cf < 4; cf++) {
            short8 bk = *(const short8*)&Ks[(cf * 16 + lr) * AST + ks * 32 + quad * 8];
            s[cf] = __builtin_amdgcn_mfma_f32_16x16x32_bf16(aq[ks], bk, s[cf], 0, 0, 0);
        }
    }
    if (diag) {
#pragma unroll
        for (int cf = 0; cf < 4; cf++) {
            int key = cf * 16 + lr;
#pragma unroll
            for (int r = 0; r < 4; r++)
                if (key > w * 16 + quad * 4 + r) s[cf][r] = -1e30f;
        }
    }
    float corr[4];
#pragma unroll
    for (int r = 0; r < 4; r++) {
        float rm = fmaxf(fmaxf(s[0][r], s[1][r]), fmaxf(s[2][r], s[3][r]));
        rm = fmaxf(rm, __shfl_xor(rm, 1));
        rm = fmaxf(rm, __shfl_xor(rm, 2));
        rm = fmaxf(rm, __shfl_xor(rm, 4));
        rm = fmaxf(rm, __shfl_xor(rm, 8));
        float mn = fmaxf(mrow[r], rm);
        corr[r] = EXP2F(mrow[r] - mn);
        mrow[r] = mn;
        float rs = 0.f;
#pragma unroll
        for (int cf = 0; cf < 4; cf++) {
            float p = EXP2F(s[cf][r] - mn);
            union { float f; unsigned int u; } px{p};
            px.u &= 0xFFFF0000u;               // truncate to bf16 (consistent l)
            Ps[(w * 16 + quad * 4 + r) * AST + cf * 16 + lr] =
                (unsigned short)(px.u >> 16);
            rs += px.f;
        }
        rs += __shfl_xor(rs, 1);
        rs += __shfl_xor(rs, 2);
        rs += __shfl_xor(rs, 4);
        rs += __shfl_xor(rs, 8);
        lrow[r] = lrow[r] * corr[r] + rs;
    }
#pragma unroll
    for (int cf = 0; cf < 4; cf++)
#pragma unroll
        for (int r = 0; r < 4; r++) oacc[cf][r] *= corr[r];
#pragma unroll
    for (int ks = 0; ks < 2; ks++) {
        short8 ap = *(const short8*)&Ps[(w * 16 + lr) * AST + ks * 32 + quad * 8];
#pragma unroll
        for (int cf = 0; cf < 4; cf++) {
            short8 bv = *(const short8*)&Vt[(cf * 16 + lr) * AST + ks * 32 + quad * 8];
            oacc[cf] = __builtin_amdgcn_mfma_f32_16x16x32_bf16(ap, bv, oacc[cf], 0, 0, 0);
        }
    }
}

__global__ __launch_bounds__(256) void attn_mfma_kernel(
        const unsigned short* __restrict__ qkv,   // [M_ROWS][QKV_N] bf16
        unsigned short* __restrict__ obf) {       // [M_ROWS][D_MODEL] bf16
    __shared__ unsigned short Ks[64 * AST];
    __shared__ unsigned short Vt[64 * AST];
    __shared__ unsigned short Ps[64 * AST];
    const int tid = threadIdx.x;
    const int w = tid >> 6, lane = tid & 63;
    const int lr = lane & 15, quad = lane >> 4;
    const int h = blockIdx.y, b = blockIdx.z;
    const int kvh = h >> 2;
    const unsigned short* kb = qkv + (size_t)(b * S_LEN) * QKV_N + KOFF + kvh * D_K;
    const unsigned short* vb = qkv + (size_t)(b * S_LEN) * QKV_N + VOFF + kvh * D_K;

    const int qtA = blockIdx.x;        // 0..7
    const int qtB = 15 - qtA;          // 8..15
    const int ntA = qtA + 1, ntB = qtB + 1;

    short8 aqA[2], aqB[2];
    {
        const unsigned short* qp = qkv + (size_t)(b * S_LEN + qtA * 64 + w * 16 + lr) * QKV_N
                                   + h * D_K + quad * 8;
        aqA[0] = *(const short8*)qp;
        aqA[1] = *(const short8*)(qp + 32);
        qp = qkv + (size_t)(b * S_LEN + qtB * 64 + w * 16 + lr) * QKV_N + h * D_K + quad * 8;
        aqB[0] = *(const short8*)qp;
        aqB[1] = *(const short8*)(qp + 32);
    }
    f32x4 oaccA[4], oaccB[4];
#pragma unroll
    for (int cf = 0; cf < 4; cf++) {
        oaccA[cf] = (f32x4){0.f, 0.f, 0.f, 0.f};
        oaccB[cf] = (f32x4){0.f, 0.f, 0.f, 0.f};
    }
    float mA[4] = {-1e30f, -1e30f, -1e30f, -1e30f}, lA[4] = {0.f, 0.f, 0.f, 0.f};
    float mB[4] = {-1e30f, -1e30f, -1e30f, -1e30f}, lB[4] = {0.f, 0.f, 0.f, 0.f};

    for (int t = 0; t < ntB; t++) {
        const int j0 = t * 64;
        __syncthreads();
        // stage K tile [64 keys][64 dims]
#pragma unroll
        for (int it = 0; it < 2; it++) {
            int f = it * 256 + tid;
            int key = f >> 3, d8 = (f & 7) * 8;
            *(uint4*)&Ks[key * AST + d8] =
                *(const uint4*)(kb + (size_t)(j0 + key) * QKV_N + d8);
        }
        // stage V transposed: Vt[dim][key], u32 pair-packed writes
        {
            int kp = tid & 31, dg = tid >> 5;    // key pair, dim group (8 dims)
            unsigned short ta[8], tb[8];
            *(uint4*)ta = *(const uint4*)(vb + (size_t)(j0 + 2 * kp) * QKV_N + dg * 8);
            *(uint4*)tb = *(const uint4*)(vb + (size_t)(j0 + 2 * kp + 1) * QKV_N + dg * 8);
#pragma unroll
            for (int i = 0; i < 8; i++) {
                unsigned int pk = (unsigned int)ta[i] | ((unsigned int)tb[i] << 16);
                *(unsigned int*)&Vt[(dg * 8 + i) * AST + 2 * kp] = pk;
            }
        }
        __syncthreads();
        if (t < ntA)
            attn_tile(w, quad, lr, t == qtA, Ks, Vt, Ps, aqA, oaccA, mA, lA);
        attn_tile(w, quad, lr, t == qtB, Ks, Vt, Ps, aqB, oaccB, mB, lB);
    }
#pragma unroll
    for (int r = 0; r < 4; r++) {
        float invA = 1.f / lA[r], invB = 1.f / lB[r];
        int rowA = b * S_LEN + qtA * 64 + w * 16 + quad * 4 + r;
        int rowB = b * S_LEN + qtB * 64 + w * 16 + quad * 4 + r;
#pragma unroll
        for (int cf = 0; cf < 4; cf++) {
            obf[(size_t)rowA * D_MODEL + h * D_K + cf * 16 + lr] = f2bf(oaccA[cf][r] * invA);
            obf[(size_t)rowB * D_MODEL + h * D_K + cf * 16 + lr] = f2bf(oaccB[cf][r] * invB);
        }
    }
}

extern "C" void kernel_launch(void* const* d_in, const int* in_sizes, int n_in,
                              void* d_out, int out_size, void* d_ws, size_t ws_size,
                              hipStream_t stream) {
    const float* x  = (const float*)d_in[0];
    const float* Wq = (const float*)d_in[1];
    const float* bq = (const float*)d_in[2];
    const float* Wk = (const float*)d_in[3];
    const float* bk = (const float*)d_in[4];
    const float* Wv = (const float*)d_in[5];
    const float* bv = (const float*)d_in[6];
    const float* Wo = (const float*)d_in[7];
    const float* bo = (const float*)d_in[8];
    float* out = (float*)d_out;

    // ws (bf16 elems): xbf/obf 8MB | WtQKV 12MB | WtO 8MB | qkv 12MB | bias 12KB = 40MB
    unsigned short* xbf   = (unsigned short*)d_ws;                       // [2048][2048]
    unsigned short* WtQKV = xbf + (size_t)M_ROWS * D_MODEL;              // [3072][2048]
    unsigned short* WtO   = WtQKV + (size_t)QKV_N * D_MODEL;             // [2048][2048]
    unsigned short* qkv   = WtO + (size_t)D_MODEL * D_MODEL;             // [2048][3072]
    float* bias_qkv       = (float*)(qkv + (size_t)M_ROWS * QKV_N);      // [3072]
    unsigned short* obf   = xbf;  // xbf consumed by QKV GEMM before attn writes

    dim3 tb(32, 8);
    dim3 gb(256);

    cast_bf_kernel<<<(M_ROWS * D_MODEL / 4 + 255) / 256, gb, 0, stream>>>(x, xbf, M_ROWS * D_MODEL / 4);
    transpose_cast_kernel<<<dim3(D_MODEL / 32, D_MODEL / 32), tb, 0, stream>>>(Wq, WtQKV, D_MODEL, D_MODEL);
    transpose_cast_kernel<<<dim3(KV_DIM / 32, D_MODEL / 32), tb, 0, stream>>>(Wk, WtQKV + (size_t)KOFF * D_MODEL, D_MODEL, KV_DIM);
    transpose_cast_kernel<<<dim3(KV_DIM / 32, D_MODEL / 32), tb, 0, stream>>>(Wv, WtQKV + (size_t)VOFF * D_MODEL, D_MODEL, KV_DIM);
    transpose_cast_kernel<<<dim3(D_MODEL / 32, D_MODEL / 32), tb, 0, stream>>>(Wo, WtO, D_MODEL, D_MODEL);
    concat_bias_kernel<<<(QKV_N + 255) / 256, gb, 0, stream>>>(bq, bk, bv, bias_qkv);
    // fused QKV projection (bf16 out): 48 x 16 = 768 blocks
    gemm_bf16_kernel<unsigned short><<<dim3(QKV_N / 64, M_ROWS / 128), gb, 0, stream>>>(
        xbf, WtQKV, bias_qkv, qkv, M_ROWS, QKV_N, D_MODEL);
    // fused RoPE (q scaled by 0.125*log2e for exp2 softmax)
    rope_bf_kernel<<<(M_ROWS * (N_HEAD + N_KV_HEAD) * 32 + 255) / 256, gb, 0, stream>>>(qkv);
    // attention
    attn_mfma_kernel<<<dim3(8, N_HEAD, B_SZ), gb, 0, stream>>>(qkv, obf);
    // O projection (fp32 out): 32 x 16 = 512 blocks
    gemm_bf16_kernel<float><<<dim3(D_MODEL / 64, M_ROWS / 128), gb, 0, stream>>>(
        obf, WtO, bo, out, M_ROWS, D_MODEL, D_MODEL);
}